// Round 3
// baseline (115.880 us; speedup 1.0000x reference)
//
#include <hip/hip_runtime.h>
#include <hip/hip_bf16.h>
#include <math.h>

#define BATCH 4096
#define NROW  8192
#define DIM   256

// zb holds bf16( sqrt(2*log2e) * z_hat ), so MFMA acc = 2*log2(e)*sim and
// exp(2*sim) == exp2(acc) — one v_exp_f32 per element, no mul.
#define SCALE_IN 1.69864360f              /* sqrt(2*1.4426950408889634) */
#define LN2      0.69314718055994531f     /* converts acc-units back to 2*sim */

typedef __attribute__((ext_vector_type(8))) short  short8;   // 8 bf16 / 4 VGPRs
typedef __attribute__((ext_vector_type(4))) float  floatx4;  // MFMA C/D

// ---------------------------------------------------------------------------
// ws layout:
//   zb     @ 0          : ushort[8192][256]  (4 MiB)  scaled-normalized bf16
//   part   @ 4 MiB      : float[8192]        row+col sums of exp (atomic)
//   bpart  @ 4 MiB+36864: float[2048]        per-block loss partials
// Fixed harness tax ~55 us/replay (256 MiB ws poison-fill at ~6 TB/s).
//
// R9: REVERT to the R6 skeleton (98.3 us session-best: single Bt, two
// barriers/ct, plain reg staging, no setprio, no runtime ping-pong) — R7/R8
// both demoted registers to scratch (VGPR_Count=64, WRITE 22-52 MB) and both
// sat at 51.8 us with every pipe <15% busy. Evidence notes:
//  * SQ_LDS_BANK_CONFLICT was bit-identical (2162688) across stride-264/288/
//    XOR-swizzle: 8 lanes per 16B slot is pigeonhole-forced for wave64
//    ds_read_b128 — B-read "conflicts" are structural, not a lever.
//  * ONE surgical change vs R6: the per-cs column tail (2 shfl + per-wave
//    scol[8][256] LDS RMW, ~100+ serial cyc x16 per wave) becomes a single
//    fire-and-forget ds_add_f32 into a SHARED scol[256] (atomicAdd, result
//    unused -> no-return form, wave never stalls). Also shrinks LDS
//    41.9 KB -> 34.8 KB and deletes the 8-way final fold.
// ---------------------------------------------------------------------------

// Wave-per-row: load fp32 row, L2-normalize, scale, write bf16. Also zeroes part.
__global__ __launch_bounds__(256) void k_prep(const float* __restrict__ z1,
                                              const float* __restrict__ z2,
                                              ushort* __restrict__ zb,
                                              float* __restrict__ part) {
  if (threadIdx.x < 4) part[blockIdx.x * 4 + threadIdx.x] = 0.f;

  int row  = blockIdx.x * 4 + (threadIdx.x >> 6);
  int lane = threadIdx.x & 63;
  const float4* src = (row < BATCH) ? (const float4*)(z1 + (size_t)row * DIM)
                                    : (const float4*)(z2 + (size_t)(row - BATCH) * DIM);
  float4 v = src[lane];
  float ss = v.x * v.x + v.y * v.y + v.z * v.z + v.w * v.w;
#pragma unroll
  for (int off = 1; off < 64; off <<= 1) ss += __shfl_xor(ss, off, 64);
  float s = SCALE_IN / fmaxf(sqrtf(ss), 1e-12f);
  __hip_bfloat16 h0 = __float2bfloat16(v.x * s), h1 = __float2bfloat16(v.y * s);
  __hip_bfloat16 h2 = __float2bfloat16(v.z * s), h3 = __float2bfloat16(v.w * s);
  ushort4 hb = {*(ushort*)&h0, *(ushort*)&h1, *(ushort*)&h2, *(ushort*)&h3};
  ((ushort4*)(zb + (size_t)row * DIM))[lane] = hb;
}

// ---------------------------------------------------------------------------
// Symmetric tile kernel: 528 blocks (upper triangle of the 32x32 grid of
// 256x256 sim tiles), 512 threads / 8 waves. Wave owns 32 rows: Af[2][8] =
// 64 pinned VGPRs. B staged in LDS 64-col chunks, stride 264 (R6 layout).
// MFMA 16x16x32_bf16: A[m=lane&15][k=quad*8+j]; B[k][n=lane&15];
//                     C/D row=quad*4+reg, col=lane&15.
// ---------------------------------------------------------------------------
__global__ __launch_bounds__(512, 4) void k_simsum(const ushort* __restrict__ zb,
                                                   float* __restrict__ part) {
  __shared__ __align__(16) ushort Bt[64 * 264];   // 33792 B, +8 pad
  __shared__ float scol[256];                     // 1024 B  (34816 B total)

  // upper-triangle decode on the 32-grid: S(r) = r*(65-r)/2 blocks before row r
  int b = blockIdx.x;
  int r = (int)((65.0f - sqrtf(65.0f * 65.0f - 8.0f * (float)b)) * 0.5f);
  r = (r > 31) ? 31 : ((r < 0) ? 0 : r);
  while ((r + 1) * (65 - (r + 1)) / 2 <= b) r++;
  while (r * (65 - r) / 2 > b) r--;
  int c = r + (b - r * (65 - r) / 2);
  const bool diag = (r == c);

  const int tid  = threadIdx.x;          // 0..511
  const int w    = tid >> 6;             // wave 0..7
  const int lane = tid & 63;
  const int quad = lane >> 4;
  const int l16  = lane & 15;
  const int rowbase = r * 256 + w * 32;  // wave's 32 rows
  const int cbase   = c * 256;

  if (tid < 256) scol[tid] = 0.f;

  // Pin A fragments: 2 rowblocks x 8 k-steps = 64 VGPRs
  short8 Af[2][8];
#pragma unroll
  for (int rb = 0; rb < 2; rb++) {
    const ushort* p = zb + (size_t)(rowbase + rb * 16 + l16) * DIM + quad * 8;
#pragma unroll
    for (int k = 0; k < 8; k++) Af[rb][k] = *(const short8*)(p + k * 32);
  }

  float rsum[2][4];
#pragma unroll
  for (int rb = 0; rb < 2; rb++)
#pragma unroll
    for (int rr = 0; rr < 4; rr++) rsum[rb][rr] = 0.f;

#pragma unroll 1
  for (int ct = 0; ct < 4; ct++) {
    const int c0 = cbase + ct * 64;
    __syncthreads();
    {
      // stage 64 rows x 256 ushort (32 KB) = 2048 uint4, 4 per thread
      const uint4* src = (const uint4*)(zb + (size_t)c0 * DIM);
#pragma unroll
      for (int i = 0; i < 4; i++) {
        int idx = tid + i * 512;
        int rr = idx >> 5, cc = idx & 31;
        *(uint4*)(&Bt[rr * 264 + cc * 8]) = src[rr * 32 + cc];
      }
    }
    __syncthreads();

#pragma unroll
    for (int cs = 0; cs < 4; cs++) {
      const ushort* bp = &Bt[(cs * 16 + l16) * 264 + quad * 8];
      floatx4 acc0 = {0.f, 0.f, 0.f, 0.f};
      floatx4 acc1 = {0.f, 0.f, 0.f, 0.f};
#pragma unroll
      for (int k = 0; k < 8; k++) {
        short8 Bf = *(const short8*)(bp + k * 32);
        acc0 = __builtin_amdgcn_mfma_f32_16x16x32_bf16(Af[0][k], Bf, acc0, 0, 0, 0);
        acc1 = __builtin_amdgcn_mfma_f32_16x16x32_bf16(Af[1][k], Bf, acc1, 0, 0, 0);
      }
      float ca = 0.f;
#pragma unroll
      for (int rr = 0; rr < 4; rr++) {
        float e0 = __builtin_amdgcn_exp2f(acc0[rr]);
        float e1 = __builtin_amdgcn_exp2f(acc1[rr]);
        rsum[0][rr] += e0;
        rsum[1][rr] += e1;
        ca += e0 + e1;
      }
      if (!diag) {
        // lane's partial for col ct*64+cs*16+l16 over its 8 rows.
        // ds_add_f32 (result unused -> no-return): fire-and-forget, no shfl,
        // no RMW chain. 4 quads collide per address; LDS atomic unit absorbs.
        atomicAdd(&scol[ct * 64 + cs * 16 + l16], ca);
      }
    }
  }

  // Row sums: reduce over the 16 column-lanes, atomics from l16==0 lanes.
#pragma unroll
  for (int rb = 0; rb < 2; rb++)
#pragma unroll
    for (int rr = 0; rr < 4; rr++) {
      float v = rsum[rb][rr];
#pragma unroll
      for (int off = 1; off < 16; off <<= 1) v += __shfl_xor(v, off, 64);
      if (l16 == 0)
        atomicAdd(&part[rowbase + rb * 16 + quad * 4 + rr], v);
    }

  // Column sums (symmetry): scol now holds the whole block's partials.
  if (!diag) {
    __syncthreads();
    if (tid < 256)
      atomicAdd(&part[cbase + tid], scol[tid]);   // 256 coalesced lane-atomics
  }
}

// ---------------------------------------------------------------------------
// Wave-per-row loss term. 2048 blocks x 256 threads (4 rows/block).
//   neg_j = part[j] - exp2(selfdot_acc_j)    (matches the matmul diagonal)
//   t_j   = log(neg_j) - dp_acc_j * ln2      (dp_acc = 2*log2e*sim_pair)
// ---------------------------------------------------------------------------
__global__ __launch_bounds__(256) void k_rowterm(const ushort* __restrict__ zb,
                                                 const float* __restrict__ part,
                                                 float* __restrict__ bpart) {
  int j    = blockIdx.x * 4 + (threadIdx.x >> 6);
  int lane = threadIdx.x & 63;
  int pj   = (j + BATCH) & (NROW - 1);
  ushort4 ua = ((const ushort4*)(zb + (size_t)j  * DIM))[lane];
  ushort4 ub = ((const ushort4*)(zb + (size_t)pj * DIM))[lane];
  uint t;
  float ax, ay, az, aw, bx, by, bz, bw;
  t = (uint)ua.x << 16; ax = *(float*)&t;  t = (uint)ua.y << 16; ay = *(float*)&t;
  t = (uint)ua.z << 16; az = *(float*)&t;  t = (uint)ua.w << 16; aw = *(float*)&t;
  t = (uint)ub.x << 16; bx = *(float*)&t;  t = (uint)ub.y << 16; by = *(float*)&t;
  t = (uint)ub.z << 16; bz = *(float*)&t;  t = (uint)ub.w << 16; bw = *(float*)&t;
  float dp = ax * bx + ay * by + az * bz + aw * bw;
  float sd = ax * ax + ay * ay + az * az + aw * aw;
#pragma unroll
  for (int off = 1; off < 64; off <<= 1) {
    dp += __shfl_xor(dp, off, 64);
    sd += __shfl_xor(sd, off, 64);
  }
  __shared__ float sred[4];
  if (lane == 0) {
    float neg = part[j] - __builtin_amdgcn_exp2f(sd);
    sred[threadIdx.x >> 6] = logf(neg) - dp * LN2;
  }
  __syncthreads();
  if (threadIdx.x == 0)
    bpart[blockIdx.x] = sred[0] + sred[1] + sred[2] + sred[3];
}

__global__ void k_final(const float* __restrict__ bpart, float* __restrict__ out) {
  int t = threadIdx.x;  // 256 threads
  float v = 0.f;
#pragma unroll
  for (int i = 0; i < 8; i++) v += bpart[t + i * 256];
  int lane = t & 63;
#pragma unroll
  for (int off = 1; off < 64; off <<= 1) v += __shfl_xor(v, off, 64);
  __shared__ float sred[4];
  if (lane == 0) sred[t >> 6] = v;
  __syncthreads();
  if (t == 0) out[0] = (sred[0] + sred[1] + sred[2] + sred[3]) / (float)NROW;
}

extern "C" void kernel_launch(void* const* d_in, const int* in_sizes, int n_in,
                              void* d_out, int out_size, void* d_ws, size_t ws_size,
                              hipStream_t stream) {
  const float* z1 = (const float*)d_in[0];
  const float* z2 = (const float*)d_in[1];
  float* out = (float*)d_out;

  char* ws = (char*)d_ws;
  ushort* zb    = (ushort*)ws;                                   // 4 MiB
  float*  part  = (float*)(ws + (size_t)4 * 1024 * 1024);        // 32 KiB
  float*  bpart = (float*)(ws + (size_t)4 * 1024 * 1024 + 36864);

  k_prep<<<NROW / 4, 256, 0, stream>>>(z1, z2, zb, part);
  k_simsum<<<528, 512, 0, stream>>>(zb, part);
  k_rowterm<<<NROW / 4, 256, 0, stream>>>(zb, part, bpart);
  k_final<<<1, 256, 0, stream>>>(bpart, out);
}

// Round 4
// 112.427 us; speedup vs baseline: 1.0307x; 1.0307x over previous
//
#include <hip/hip_runtime.h>
#include <hip/hip_bf16.h>
#include <math.h>

#define BATCH 4096
#define NROW  8192
#define DIM   256

// zb holds bf16( sqrt(2*log2e) * z_hat ), so MFMA acc = 2*log2(e)*sim and
// exp(2*sim) == exp2(acc) — one v_exp_f32 per element, no mul.
#define SCALE_IN 1.69864360f              /* sqrt(2*1.4426950408889634) */
#define LN2      0.69314718055994531f     /* converts acc-units back to 2*sim */

typedef __attribute__((ext_vector_type(8))) short  short8;   // 8 bf16 / 4 VGPRs
typedef __attribute__((ext_vector_type(4))) float  floatx4;  // MFMA C/D

// ---------------------------------------------------------------------------
// ws layout:
//   zb     @ 0          : ushort[8192][256]  (4 MiB)  scaled-normalized bf16
//   part   @ 4 MiB      : float[8192]        row+col sums of exp (atomic)
//   bpart  @ 4 MiB+36864: float[2048]        per-block loss partials
// Fixed harness tax ~55 us/replay (256 MiB ws poison-fill at ~6 TB/s).
//
// R10: decomposition fix. Evidence from R6-R9:
//  * R9 did NOT spill (WRITE 2.6 MB; an Af spill would be >=67 MB). The
//    VGPR_Count=64 is arch-VGPRs only; Af lives in the AGPR half (legal MFMA
//    A-operand on gfx950 unified file). Register demotion was R7-only.
//  * R9's LDS-atomic col tail cost +13 us (4-way same-address ds_add
//    serialization on the shared LDS pipe) — reverted to R6 shfl+scol.
//  * Real bottleneck: Occupancy 25% = ONE 512-thread block/CU, 8 waves in
//    barrier lockstep through 16 serial phases; 528 blocks -> 16 CUs run 3
//    sequential blocks (50% tail). Latency-bound, every pipe <15%.
//  FIX: same inner loop, 128x128 tiles on the 64x64 triangle grid ->
//  2080 blocks x 256 thr (4 waves). 36 KB LDS -> 4 blocks/CU co-resident;
//  independent blocks overlap stage/MFMA phases naturally (m114), tail
//  imbalance 50% -> 12.5%.
// ---------------------------------------------------------------------------

// Wave-per-row: load fp32 row, L2-normalize, scale, write bf16. Also zeroes part.
__global__ __launch_bounds__(256) void k_prep(const float* __restrict__ z1,
                                              const float* __restrict__ z2,
                                              ushort* __restrict__ zb,
                                              float* __restrict__ part) {
  if (threadIdx.x < 4) part[blockIdx.x * 4 + threadIdx.x] = 0.f;

  int row  = blockIdx.x * 4 + (threadIdx.x >> 6);
  int lane = threadIdx.x & 63;
  const float4* src = (row < BATCH) ? (const float4*)(z1 + (size_t)row * DIM)
                                    : (const float4*)(z2 + (size_t)(row - BATCH) * DIM);
  float4 v = src[lane];
  float ss = v.x * v.x + v.y * v.y + v.z * v.z + v.w * v.w;
#pragma unroll
  for (int off = 1; off < 64; off <<= 1) ss += __shfl_xor(ss, off, 64);
  float s = SCALE_IN / fmaxf(sqrtf(ss), 1e-12f);
  __hip_bfloat16 h0 = __float2bfloat16(v.x * s), h1 = __float2bfloat16(v.y * s);
  __hip_bfloat16 h2 = __float2bfloat16(v.z * s), h3 = __float2bfloat16(v.w * s);
  ushort4 hb = {*(ushort*)&h0, *(ushort*)&h1, *(ushort*)&h2, *(ushort*)&h3};
  ((ushort4*)(zb + (size_t)row * DIM))[lane] = hb;
}

// ---------------------------------------------------------------------------
// Symmetric tile kernel: 2080 blocks (upper triangle of the 64x64 grid of
// 128x128 sim tiles), 256 threads / 4 waves. Wave owns 32 rows: Af[2][8] =
// 64 regs (AGPR half). B staged in LDS 64-col chunks, stride 264 (R6 layout).
// 36 KB LDS, ~128 regs/wave -> 4 blocks/CU co-resident; cross-block overlap
// replaces intra-block pipelining (which R7/R8 proved counterproductive).
// MFMA 16x16x32_bf16: A[m=lane&15][k=quad*8+j]; B[k][n=lane&15];
//                     C/D row=quad*4+reg, col=lane&15.
// ---------------------------------------------------------------------------
__global__ __launch_bounds__(256, 4) void k_simsum(const ushort* __restrict__ zb,
                                                   float* __restrict__ part) {
  __shared__ __align__(16) ushort Bt[64 * 264];   // 33792 B, +8 pad
  __shared__ float scol[4][128];                  // 2048 B  (35840 B total)

  // upper-triangle decode on the 64-grid: S(r) = r*(129-r)/2 blocks before row r
  int b = blockIdx.x;
  int r = (int)((129.0f - sqrtf(16641.0f - 8.0f * (float)b)) * 0.5f);
  r = (r > 63) ? 63 : ((r < 0) ? 0 : r);
  while ((r + 1) * (129 - (r + 1)) / 2 <= b) r++;
  while (r * (129 - r) / 2 > b) r--;
  int c = r + (b - r * (129 - r) / 2);
  const bool diag = (r == c);

  const int tid  = threadIdx.x;          // 0..255
  const int w    = tid >> 6;             // wave 0..3
  const int lane = tid & 63;
  const int quad = lane >> 4;
  const int l16  = lane & 15;
  const int rowbase = r * 128 + w * 32;  // wave's 32 rows
  const int cbase   = c * 128;

  {
    float* sf = (float*)scol;
    sf[tid] = 0.f; sf[tid + 256] = 0.f;   // 512 floats
  }

  // Pin A fragments: 2 rowblocks x 8 k-steps = 64 regs
  short8 Af[2][8];
#pragma unroll
  for (int rb = 0; rb < 2; rb++) {
    const ushort* p = zb + (size_t)(rowbase + rb * 16 + l16) * DIM + quad * 8;
#pragma unroll
    for (int k = 0; k < 8; k++) Af[rb][k] = *(const short8*)(p + k * 32);
  }

  float rsum[2][4];
#pragma unroll
  for (int rb = 0; rb < 2; rb++)
#pragma unroll
    for (int rr = 0; rr < 4; rr++) rsum[rb][rr] = 0.f;

#pragma unroll 1
  for (int ct = 0; ct < 2; ct++) {
    const int c0 = cbase + ct * 64;
    __syncthreads();
    {
      // stage 64 rows x 256 ushort (32 KB) = 2048 uint4, 8 per thread
      const uint4* src = (const uint4*)(zb + (size_t)c0 * DIM);
#pragma unroll
      for (int i = 0; i < 8; i++) {
        int idx = tid + i * 256;
        int rr = idx >> 5, cc = idx & 31;
        *(uint4*)(&Bt[rr * 264 + cc * 8]) = src[rr * 32 + cc];
      }
    }
    __syncthreads();

#pragma unroll
    for (int cs = 0; cs < 4; cs++) {
      const ushort* bp = &Bt[(cs * 16 + l16) * 264 + quad * 8];
      floatx4 acc0 = {0.f, 0.f, 0.f, 0.f};
      floatx4 acc1 = {0.f, 0.f, 0.f, 0.f};
#pragma unroll
      for (int k = 0; k < 8; k++) {
        short8 Bf = *(const short8*)(bp + k * 32);
        acc0 = __builtin_amdgcn_mfma_f32_16x16x32_bf16(Af[0][k], Bf, acc0, 0, 0, 0);
        acc1 = __builtin_amdgcn_mfma_f32_16x16x32_bf16(Af[1][k], Bf, acc1, 0, 0, 0);
      }
      float ca = 0.f;
#pragma unroll
      for (int rr = 0; rr < 4; rr++) {
        float e0 = __builtin_amdgcn_exp2f(acc0[rr]);
        float e1 = __builtin_amdgcn_exp2f(acc1[rr]);
        rsum[0][rr] += e0;
        rsum[1][rr] += e1;
        ca += e0 + e1;
      }
      if (!diag) {
        // ca covers this wave's 32 rows for col (ct*64+cs*16+l16); fold quads
        ca += __shfl_xor(ca, 16, 64);
        ca += __shfl_xor(ca, 32, 64);
        if (quad == 0)
          scol[w][ct * 64 + cs * 16 + l16] += ca;   // 16 lanes, 16 banks
      }
    }
  }

  // Row sums: reduce over the 16 column-lanes, atomics from l16==0 lanes.
#pragma unroll
  for (int rb = 0; rb < 2; rb++)
#pragma unroll
    for (int rr = 0; rr < 4; rr++) {
      float v = rsum[rb][rr];
#pragma unroll
      for (int off = 1; off < 16; off <<= 1) v += __shfl_xor(v, off, 64);
      if (l16 == 0)
        atomicAdd(&part[rowbase + rb * 16 + quad * 4 + rr], v);
    }

  // Column sums (symmetry).
  if (!diag) {
    __syncthreads();
    if (tid < 128) {
      float v = scol[0][tid] + scol[1][tid] + scol[2][tid] + scol[3][tid];
      atomicAdd(&part[cbase + tid], v);   // 128 coalesced lane-atomics
    }
  }
}

// ---------------------------------------------------------------------------
// Wave-per-row loss term. 2048 blocks x 256 threads (4 rows/block).
//   neg_j = part[j] - exp2(selfdot_acc_j)    (matches the matmul diagonal)
//   t_j   = log(neg_j) - dp_acc_j * ln2      (dp_acc = 2*log2e*sim_pair)
// ---------------------------------------------------------------------------
__global__ __launch_bounds__(256) void k_rowterm(const ushort* __restrict__ zb,
                                                 const float* __restrict__ part,
                                                 float* __restrict__ bpart) {
  int j    = blockIdx.x * 4 + (threadIdx.x >> 6);
  int lane = threadIdx.x & 63;
  int pj   = (j + BATCH) & (NROW - 1);
  ushort4 ua = ((const ushort4*)(zb + (size_t)j  * DIM))[lane];
  ushort4 ub = ((const ushort4*)(zb + (size_t)pj * DIM))[lane];
  uint t;
  float ax, ay, az, aw, bx, by, bz, bw;
  t = (uint)ua.x << 16; ax = *(float*)&t;  t = (uint)ua.y << 16; ay = *(float*)&t;
  t = (uint)ua.z << 16; az = *(float*)&t;  t = (uint)ua.w << 16; aw = *(float*)&t;
  t = (uint)ub.x << 16; bx = *(float*)&t;  t = (uint)ub.y << 16; by = *(float*)&t;
  t = (uint)ub.z << 16; bz = *(float*)&t;  t = (uint)ub.w << 16; bw = *(float*)&t;
  float dp = ax * bx + ay * by + az * bz + aw * bw;
  float sd = ax * ax + ay * ay + az * az + aw * aw;
#pragma unroll
  for (int off = 1; off < 64; off <<= 1) {
    dp += __shfl_xor(dp, off, 64);
    sd += __shfl_xor(sd, off, 64);
  }
  __shared__ float sred[4];
  if (lane == 0) {
    float neg = part[j] - __builtin_amdgcn_exp2f(sd);
    sred[threadIdx.x >> 6] = logf(neg) - dp * LN2;
  }
  __syncthreads();
  if (threadIdx.x == 0)
    bpart[blockIdx.x] = sred[0] + sred[1] + sred[2] + sred[3];
}

__global__ void k_final(const float* __restrict__ bpart, float* __restrict__ out) {
  int t = threadIdx.x;  // 256 threads
  float v = 0.f;
#pragma unroll
  for (int i = 0; i < 8; i++) v += bpart[t + i * 256];
  int lane = t & 63;
#pragma unroll
  for (int off = 1; off < 64; off <<= 1) v += __shfl_xor(v, off, 64);
  __shared__ float sred[4];
  if (lane == 0) sred[t >> 6] = v;
  __syncthreads();
  if (t == 0) out[0] = (sred[0] + sred[1] + sred[2] + sred[3]) / (float)NROW;
}

extern "C" void kernel_launch(void* const* d_in, const int* in_sizes, int n_in,
                              void* d_out, int out_size, void* d_ws, size_t ws_size,
                              hipStream_t stream) {
  const float* z1 = (const float*)d_in[0];
  const float* z2 = (const float*)d_in[1];
  float* out = (float*)d_out;

  char* ws = (char*)d_ws;
  ushort* zb    = (ushort*)ws;                                   // 4 MiB
  float*  part  = (float*)(ws + (size_t)4 * 1024 * 1024);        // 32 KiB
  float*  bpart = (float*)(ws + (size_t)4 * 1024 * 1024 + 36864);

  k_prep<<<NROW / 4, 256, 0, stream>>>(z1, z2, zb, part);
  k_simsum<<<2080, 256, 0, stream>>>(zb, part);
  k_rowterm<<<NROW / 4, 256, 0, stream>>>(zb, part, bpart);
  k_final<<<1, 256, 0, stream>>>(bpart, out);
}

// Round 5
// 99.403 us; speedup vs baseline: 1.1658x; 1.1310x over previous
//
#include <hip/hip_runtime.h>
#include <hip/hip_bf16.h>
#include <math.h>

#define BATCH 4096
#define NROW  8192
#define DIM   256

// zb holds bf16( sqrt(2*log2e) * z_hat ), so MFMA acc = 2*log2(e)*sim and
// exp(2*sim) == exp2(acc) — one v_exp_f32 per element, no mul.
#define SCALE_IN 1.69864360f              /* sqrt(2*1.4426950408889634) */
#define LN2      0.69314718055994531f     /* converts acc-units back to 2*sim */

typedef __attribute__((ext_vector_type(8))) short  short8;   // 8 bf16 / 4 VGPRs
typedef __attribute__((ext_vector_type(4))) float  floatx4;  // MFMA C/D

// ---------------------------------------------------------------------------
// R11 = byte-for-byte resubmission of the round-0 session-best artifact
// (measured 98.3 us there). A/A calibration: R7(spill)/R8(DMA)/R10(128-tile)
// — three mechanistically different k_simsum variants — all measured 51.5 us
// +/-0.7%, which is more consistent with an environment/clock drift after
// round 0 than with three independent bottlenecks coinciding. This run
// disambiguates: ~98 us => baseline trusted, regressions real, resume with
// single isolated changes; ~112 us => drift proven, re-rank variants within
// the current environment and treat 51.5 as the current-machine floor.
//
// ws layout:
//   zb     @ 0          : ushort[8192][256]  (4 MiB)  scaled-normalized bf16
//   part   @ 4 MiB      : float[8192]        row+col sums of exp (atomic)
//   bpart  @ 4 MiB+36864: float[2048]        per-block loss partials
// Fixed harness tax ~55 us/replay (256 MiB ws poison-fill at ~6 TB/s + input
// restore + gaps) — not addressable from here.
// ---------------------------------------------------------------------------

// Wave-per-row: load fp32 row, L2-normalize, scale, write bf16. Also zeroes part.
__global__ __launch_bounds__(256) void k_prep(const float* __restrict__ z1,
                                              const float* __restrict__ z2,
                                              ushort* __restrict__ zb,
                                              float* __restrict__ part) {
  if (threadIdx.x < 4) part[blockIdx.x * 4 + threadIdx.x] = 0.f;

  int row  = blockIdx.x * 4 + (threadIdx.x >> 6);
  int lane = threadIdx.x & 63;
  const float4* src = (row < BATCH) ? (const float4*)(z1 + (size_t)row * DIM)
                                    : (const float4*)(z2 + (size_t)(row - BATCH) * DIM);
  float4 v = src[lane];
  float ss = v.x * v.x + v.y * v.y + v.z * v.z + v.w * v.w;
#pragma unroll
  for (int off = 1; off < 64; off <<= 1) ss += __shfl_xor(ss, off, 64);
  float s = SCALE_IN / fmaxf(sqrtf(ss), 1e-12f);
  __hip_bfloat16 h0 = __float2bfloat16(v.x * s), h1 = __float2bfloat16(v.y * s);
  __hip_bfloat16 h2 = __float2bfloat16(v.z * s), h3 = __float2bfloat16(v.w * s);
  ushort4 hb = {*(ushort*)&h0, *(ushort*)&h1, *(ushort*)&h2, *(ushort*)&h3};
  ((ushort4*)(zb + (size_t)row * DIM))[lane] = hb;
}

// ---------------------------------------------------------------------------
// Symmetric tile kernel: 528 blocks (upper triangle of the 32x32 grid of
// 256x256 sim tiles), 512 THREADS / 8 WAVES per block. 2 blocks/CU x 8 waves
// = 16 waves/CU (4/SIMD). Wave owns 32 rows: Af[2][8] = 64 pinned VGPRs.
// B staged in LDS 64-col chunks (pinning guarantee: ds_read can't be
// rematerialized across the barrier). Off-diag tiles accumulate col sums
// (symmetry) in per-wave LDS scol, one coalesced atomic pass at the end.
// MFMA 16x16x32_bf16: A[m=lane&15][k=quad*8+j]; B[k][n=lane&15];
//                     C/D row=quad*4+reg, col=lane&15.
// ---------------------------------------------------------------------------
__global__ __launch_bounds__(512, 4) void k_simsum(const ushort* __restrict__ zb,
                                                   float* __restrict__ part) {
  __shared__ __align__(16) ushort Bt[64 * 264];   // 33792 B, +8 pad
  __shared__ float scol[8][256];                  // 8192 B

  // upper-triangle decode on the 32-grid: S(r) = r*(65-r)/2 blocks before row r
  int b = blockIdx.x;
  int r = (int)((65.0f - sqrtf(65.0f * 65.0f - 8.0f * (float)b)) * 0.5f);
  r = (r > 31) ? 31 : ((r < 0) ? 0 : r);
  while ((r + 1) * (65 - (r + 1)) / 2 <= b) r++;
  while (r * (65 - r) / 2 > b) r--;
  int c = r + (b - r * (65 - r) / 2);
  const bool diag = (r == c);

  const int tid  = threadIdx.x;          // 0..511
  const int w    = tid >> 6;             // wave 0..7
  const int lane = tid & 63;
  const int quad = lane >> 4;
  const int l16  = lane & 15;
  const int rowbase = r * 256 + w * 32;  // wave's 32 rows
  const int cbase   = c * 256;

  {
    float* sf = (float*)scol;
    sf[tid] = 0.f; sf[tid + 512] = 0.f; sf[tid + 1024] = 0.f; sf[tid + 1536] = 0.f;
  }

  // Pin A fragments: 2 rowblocks x 8 k-steps = 64 VGPRs
  short8 Af[2][8];
#pragma unroll
  for (int rb = 0; rb < 2; rb++) {
    const ushort* p = zb + (size_t)(rowbase + rb * 16 + l16) * DIM + quad * 8;
#pragma unroll
    for (int k = 0; k < 8; k++) Af[rb][k] = *(const short8*)(p + k * 32);
  }

  float rsum[2][4];
#pragma unroll
  for (int rb = 0; rb < 2; rb++)
#pragma unroll
    for (int rr = 0; rr < 4; rr++) rsum[rb][rr] = 0.f;

#pragma unroll 1
  for (int ct = 0; ct < 4; ct++) {
    const int c0 = cbase + ct * 64;
    __syncthreads();
    {
      // stage 64 rows x 256 ushort (32 KB) = 2048 uint4, 4 per thread
      const uint4* src = (const uint4*)(zb + (size_t)c0 * DIM);
#pragma unroll
      for (int i = 0; i < 4; i++) {
        int idx = tid + i * 512;
        int rr = idx >> 5, cc = idx & 31;
        *(uint4*)(&Bt[rr * 264 + cc * 8]) = src[rr * 32 + cc];
      }
    }
    __syncthreads();

#pragma unroll
    for (int cs = 0; cs < 4; cs++) {
      const ushort* bp = &Bt[(cs * 16 + l16) * 264 + quad * 8];
      floatx4 acc0 = {0.f, 0.f, 0.f, 0.f};
      floatx4 acc1 = {0.f, 0.f, 0.f, 0.f};
#pragma unroll
      for (int k = 0; k < 8; k++) {
        short8 Bf = *(const short8*)(bp + k * 32);
        acc0 = __builtin_amdgcn_mfma_f32_16x16x32_bf16(Af[0][k], Bf, acc0, 0, 0, 0);
        acc1 = __builtin_amdgcn_mfma_f32_16x16x32_bf16(Af[1][k], Bf, acc1, 0, 0, 0);
      }
      float ca = 0.f;
#pragma unroll
      for (int rr = 0; rr < 4; rr++) {
        float e0 = __builtin_amdgcn_exp2f(acc0[rr]);
        float e1 = __builtin_amdgcn_exp2f(acc1[rr]);
        rsum[0][rr] += e0;
        rsum[1][rr] += e1;
        ca += e0 + e1;
      }
      if (!diag) {
        // ca covers this wave's 32 rows for col (ct*64+cs*16+l16); fold quads
        ca += __shfl_xor(ca, 16, 64);
        ca += __shfl_xor(ca, 32, 64);
        if (quad == 0)
          scol[w][ct * 64 + cs * 16 + l16] += ca;   // 16 lanes, 16 banks
      }
    }
  }

  // Row sums: reduce over the 16 column-lanes, atomics from l16==0 lanes.
#pragma unroll
  for (int rb = 0; rb < 2; rb++)
#pragma unroll
    for (int rr = 0; rr < 4; rr++) {
      float v = rsum[rb][rr];
#pragma unroll
      for (int off = 1; off < 16; off <<= 1) v += __shfl_xor(v, off, 64);
      if (l16 == 0)
        atomicAdd(&part[rowbase + rb * 16 + quad * 4 + rr], v);
    }

  if (!diag) {
    __syncthreads();
    if (tid < 256) {
      float v = 0.f;
#pragma unroll
      for (int ww = 0; ww < 8; ww++) v += scol[ww][tid];
      atomicAdd(&part[cbase + tid], v);   // 256 coalesced lane-atomics
    }
  }
}

// ---------------------------------------------------------------------------
// Wave-per-row loss term. 2048 blocks x 256 threads (4 rows/block).
//   neg_j = part[j] - exp2(selfdot_acc_j)    (matches the matmul diagonal)
//   t_j   = log(neg_j) - dp_acc_j * ln2      (dp_acc = 2*log2e*sim_pair)
// ---------------------------------------------------------------------------
__global__ __launch_bounds__(256) void k_rowterm(const ushort* __restrict__ zb,
                                                 const float* __restrict__ part,
                                                 float* __restrict__ bpart) {
  int j    = blockIdx.x * 4 + (threadIdx.x >> 6);
  int lane = threadIdx.x & 63;
  int pj   = (j + BATCH) & (NROW - 1);
  ushort4 ua = ((const ushort4*)(zb + (size_t)j  * DIM))[lane];
  ushort4 ub = ((const ushort4*)(zb + (size_t)pj * DIM))[lane];
  uint t;
  float ax, ay, az, aw, bx, by, bz, bw;
  t = (uint)ua.x << 16; ax = *(float*)&t;  t = (uint)ua.y << 16; ay = *(float*)&t;
  t = (uint)ua.z << 16; az = *(float*)&t;  t = (uint)ua.w << 16; aw = *(float*)&t;
  t = (uint)ub.x << 16; bx = *(float*)&t;  t = (uint)ub.y << 16; by = *(float*)&t;
  t = (uint)ub.z << 16; bz = *(float*)&t;  t = (uint)ub.w << 16; bw = *(float*)&t;
  float dp = ax * bx + ay * by + az * bz + aw * bw;
  float sd = ax * ax + ay * ay + az * az + aw * aw;
#pragma unroll
  for (int off = 1; off < 64; off <<= 1) {
    dp += __shfl_xor(dp, off, 64);
    sd += __shfl_xor(sd, off, 64);
  }
  __shared__ float sred[4];
  if (lane == 0) {
    float neg = part[j] - __builtin_amdgcn_exp2f(sd);
    sred[threadIdx.x >> 6] = logf(neg) - dp * LN2;
  }
  __syncthreads();
  if (threadIdx.x == 0)
    bpart[blockIdx.x] = sred[0] + sred[1] + sred[2] + sred[3];
}

__global__ void k_final(const float* __restrict__ bpart, float* __restrict__ out) {
  int t = threadIdx.x;  // 256 threads
  float v = 0.f;
#pragma unroll
  for (int i = 0; i < 8; i++) v += bpart[t + i * 256];
  int lane = t & 63;
#pragma unroll
  for (int off = 1; off < 64; off <<= 1) v += __shfl_xor(v, off, 64);
  __shared__ float sred[4];
  if (lane == 0) sred[t >> 6] = v;
  __syncthreads();
  if (t == 0) out[0] = (sred[0] + sred[1] + sred[2] + sred[3]) / (float)NROW;
}

extern "C" void kernel_launch(void* const* d_in, const int* in_sizes, int n_in,
                              void* d_out, int out_size, void* d_ws, size_t ws_size,
                              hipStream_t stream) {
  const float* z1 = (const float*)d_in[0];
  const float* z2 = (const float*)d_in[1];
  float* out = (float*)d_out;

  char* ws = (char*)d_ws;
  ushort* zb    = (ushort*)ws;                                   // 4 MiB
  float*  part  = (float*)(ws + (size_t)4 * 1024 * 1024);        // 32 KiB
  float*  bpart = (float*)(ws + (size_t)4 * 1024 * 1024 + 36864);

  k_prep<<<NROW / 4, 256, 0, stream>>>(z1, z2, zb, part);
  k_simsum<<<528, 512, 0, stream>>>(zb, part);
  k_rowterm<<<NROW / 4, 256, 0, stream>>>(zb, part, bpart);
  k_final<<<1, 256, 0, stream>>>(bpart, out);
}